// Round 9
// baseline (151.926 us; speedup 1.0000x reference)
//
#include <hip/hip_runtime.h>

#define B_N 8192
#define D_N 1024
#define C_N 1024
#define BM 128
#define BN 128
#define BK 64

typedef __attribute__((ext_vector_type(8))) __bf16 bf16x8;
typedef __attribute__((ext_vector_type(4))) __bf16 bf16x4;
typedef __attribute__((ext_vector_type(4))) float floatx4;

__device__ inline unsigned short f2bf(float f) {
  union { float f; unsigned int u; } cv; cv.f = f;
  unsigned int b = cv.u;
  unsigned int r = (b + 0x7FFFu + ((b >> 16) & 1u)) >> 16;  // RNE
  return (unsigned short)r;
}
__device__ inline float d4(const float4 a) {
  return a.x * a.x + a.y * a.y + a.z * a.z + a.w * a.w;
}
__device__ inline ushort4 pk4(const float4 v, const float s) {
  ushort4 u;
  u.x = f2bf(v.x * s); u.y = f2bf(v.y * s);
  u.z = f2bf(v.z * s); u.w = f2bf(v.w * s);
  return u;
}

// ---------------------------------------------------------------------------
// prep_kernel v2 (1024 fat blocks): part 1 computes ONLY the emb_j row
// inv-norms rn[row] (no z_j materialization — the gemm stages raw bf16(emb_j)
// and scales the dot by rn in its epilogue; bf16 error is scale-invariant).
// part 2: prototype for class c = blockIdx.x (unchanged R7 structure).
// ---------------------------------------------------------------------------
__global__ __launch_bounds__(256) void prep_kernel(
    const float* __restrict__ emb_i, const float* __restrict__ emb_j,
    const int* __restrict__ labels,
    float* __restrict__ rn, unsigned short* __restrict__ proto,
    float* __restrict__ p2, float* __restrict__ out) {
  __shared__ float sx[4][8];
  __shared__ int list[8];
  __shared__ int scnt;

  const int t = threadIdx.x;
  const int lane = t & 63;
  const int wid = t >> 6;
  const int blk = blockIdx.x;

  if (t == 0) scnt = 0;
  if (blk == 0 && t == 0) out[0] = 0.0f;

  // ---- part 1: inv-norms of 8 emb_j rows (one per wave per iteration) ----
#pragma unroll
  for (int it = 0; it < 2; ++it) {
    const int row = blk * 8 + it * 4 + wid;
    const float4* src = (const float4*)(emb_j + (size_t)row * D_N);
    float ss = d4(src[lane]) + d4(src[lane + 64]) +
               d4(src[lane + 128]) + d4(src[lane + 192]);
    for (int o = 32; o; o >>= 1) ss += __shfl_xor(ss, o, 64);
    if (lane == 0) rn[row] = 1.0f / fmaxf(sqrtf(ss), 1e-12f);
  }

  // ---- part 2: prototype for class c = blk ----
  const int c = blk;
  __syncthreads();  // scnt=0 visible
  const int4* lab4 = (const int4*)labels;
  for (int i = 0; i < 8; ++i) {
    const int q = i * 256 + t;
    const int4 L = lab4[q];
    const int base = q * 4;
    if (L.x == c) list[atomicAdd(&scnt, 1) & 7] = base;
    if (L.y == c) list[atomicAdd(&scnt, 1) & 7] = base + 1;
    if (L.z == c) list[atomicAdd(&scnt, 1) & 7] = base + 2;
    if (L.w == c) list[atomicAdd(&scnt, 1) & 7] = base + 3;
  }
  __syncthreads();

  const float* base = emb_i + wid * 256;
  float4 v[8];
  float ss[8];
#pragma unroll
  for (int k = 0; k < 8; ++k) {
    v[k] = ((const float4*)(base + (size_t)list[k] * D_N))[lane];
    ss[k] = d4(v[k]);
  }
#pragma unroll
  for (int k = 0; k < 8; ++k)
    for (int o = 32; o; o >>= 1) ss[k] += __shfl_xor(ss[k], o, 64);
  if (lane == 0) {
#pragma unroll
    for (int k = 0; k < 8; ++k) sx[wid][k] = ss[k];
  }
  __syncthreads();

  float4 a = make_float4(0.f, 0.f, 0.f, 0.f);
#pragma unroll
  for (int k = 0; k < 8; ++k) {
    const float tot = sx[0][k] + sx[1][k] + sx[2][k] + sx[3][k];
    const float iv = 1.0f / fmaxf(sqrtf(tot), 1e-12f);
    a.x += v[k].x * iv; a.y += v[k].y * iv;
    a.z += v[k].z * iv; a.w += v[k].w * iv;
  }
  a.x *= 0.125f; a.y *= 0.125f; a.z *= 0.125f; a.w *= 0.125f;

  float pp = d4(a);
  for (int o = 32; o; o >>= 1) pp += __shfl_xor(pp, o, 64);
  __syncthreads();
  if (lane == 0) sx[wid][0] = pp;
  __syncthreads();
  if (t == 0) p2[c] = sx[0][0] + sx[1][0] + sx[2][0] + sx[3][0];

  ((ushort4*)(proto + (size_t)c * D_N + wid * 256))[lane] = pk4(a, 1.0f);
}

// ---------------------------------------------------------------------------
// gemm_loss_kernel v4: R7 inner structure (BK=64, 16x16x32 MFMA, XOR swizzle,
// 0 conflicts) but A is staged from RAW fp32 emb_j through VGPRs
// (load float4 -> cvt bf16x4 -> ds_write_b64 into the same swizzled layout);
// the row inv-norm is applied to the DOT in the epilogue (dot*rn). B keeps
// the global_load_lds path from the bf16 proto array.
// ---------------------------------------------------------------------------
__global__ __launch_bounds__(256) void gemm_loss_kernel(
    const float* __restrict__ Ej,            // [B,D] fp32 raw emb_j
    const unsigned short* __restrict__ P,    // [C,D] bf16 prototypes
    const float* __restrict__ rn,            // [B] inv-norms of emb_j rows
    const float* __restrict__ p2,            // [C]
    const int* __restrict__ labels,          // [B]
    float* __restrict__ out) {               // scalar (zeroed by prep)
  __shared__ __align__(16) unsigned short As[BM * BK];
  __shared__ __align__(16) unsigned short Bs[BN * BK];
  __shared__ float srn[BM];
  __shared__ float sred[4];

  const int t = threadIdx.x;
  const int lane = t & 63;
  const int wid = t >> 6;
  const int wm = (wid >> 1) * 64;
  const int wn = (wid & 1) * 64;
  const int bm = blockIdx.x;
  const int bn = blockIdx.y;

  if (t < BM) srn[t] = rn[bm * BM + t];

  floatx4 acc[4][4];
#pragma unroll
  for (int i = 0; i < 4; ++i)
#pragma unroll
    for (int j = 0; j < 4; ++j)
      acc[i][j] = (floatx4){0.f, 0.f, 0.f, 0.f};

  // ---- B staging via global_load_lds (R7 path, XOR swizzle) ----
  const int srow = t >> 3;
  const int scol = (((t & 7) ^ (srow & 7)) << 3);
  const unsigned short* Bg = P + (size_t)(bn * BN + srow) * D_N + scol;
  unsigned short* Bl = Bs + t * 8;

  // ---- A staging via VGPRs from raw fp32 ----
  // thread t owns float4-column (t&15) of rows (t>>4)+16k, k=0..7.
  // LDS slot: row*64 + (chunk ^ (row&7))*8 + half*4 ushorts; chunk=(t&15)>>1,
  // half=t&1, row&7=(t>>4)&7 invariant across k (16k ≡ 0 mod 8).
  const float4* Agp = (const float4*)(Ej + (size_t)(bm * BM + (t >> 4)) * D_N) + (t & 15);
  unsigned short* Aw = As + (t >> 4) * 64 +
                       ((((t & 15) >> 1) ^ ((t >> 4) & 7)) << 3) + (t & 1) * 4;

  for (int k0 = 0; k0 < D_N; k0 += BK) {
#pragma unroll
    for (int it = 0; it < 4; ++it) {
      __builtin_amdgcn_global_load_lds(
          (const __attribute__((address_space(1))) void*)(Bg + (size_t)it * 32 * D_N + k0),
          (__attribute__((address_space(3))) void*)(Bl + it * 2048), 16, 0, 0);
    }
    const int kq = k0 >> 2;  // float4 offset within a row
#pragma unroll
    for (int k = 0; k < 8; ++k) {
      const float4 w = Agp[k * 4096 + kq];  // 16 rows * 256 float4/row
      bf16x4 bv;
      bv[0] = (__bf16)w.x; bv[1] = (__bf16)w.y;
      bv[2] = (__bf16)w.z; bv[3] = (__bf16)w.w;
      *(bf16x4*)(Aw + k * 1024) = bv;  // ds_write_b64
    }
    __syncthreads();
#pragma unroll
    for (int kk = 0; kk < BK; kk += 32) {
      const int swz = ((((kk >> 3) + (lane >> 4)) ^ (lane & 7)) << 3);
      bf16x8 af[4], bfr[4];
#pragma unroll
      for (int mi = 0; mi < 4; ++mi)
        af[mi] = *(const bf16x8*)(As + (wm + mi * 16 + (lane & 15)) * BK + swz);
#pragma unroll
      for (int ni = 0; ni < 4; ++ni)
        bfr[ni] = *(const bf16x8*)(Bs + (wn + ni * 16 + (lane & 15)) * BK + swz);
#pragma unroll
      for (int mi = 0; mi < 4; ++mi)
#pragma unroll
        for (int ni = 0; ni < 4; ++ni)
          acc[mi][ni] = __builtin_amdgcn_mfma_f32_16x16x32_bf16(af[mi], bfr[ni], acc[mi][ni], 0, 0, 0);
    }
    __syncthreads();
  }

  // epilogue: C/D layout col=lane&15, row=(lane>>4)*4+reg; dot scaled by rn.
  const int colb = bn * BN + wn + (lane & 15);
  const int rowloc = wm + ((lane >> 4) << 2);
  float p2c[4];
#pragma unroll
  for (int ni = 0; ni < 4; ++ni) p2c[ni] = p2[colb + ni * 16];

  float lsum = 0.f;
#pragma unroll
  for (int mi = 0; mi < 4; ++mi) {
#pragma unroll
    for (int r = 0; r < 4; ++r) {
      const int rl = rowloc + mi * 16 + r;
      const float rv = srn[rl];
      const int lab = labels[bm * BM + rl];
#pragma unroll
      for (int ni = 0; ni < 4; ++ni) {
        const float dot = acc[mi][ni][r] * rv;
        const float d2 = 1.0f + p2c[ni] - 2.0f * dot;
        const float s = 2.0f - sqrtf(fmaxf(d2, 0.0f));
        const float sp = fmaxf(s, 0.0f) + log1pf(expf(-fabsf(s)));
        lsum += sp - ((lab == colb + ni * 16) ? s : 0.0f);
      }
    }
  }
  for (int o = 32; o; o >>= 1) lsum += __shfl_xor(lsum, o, 64);
  if (lane == 0) sred[wid] = lsum;
  __syncthreads();
  if (t == 0)
    atomicAdd(out, (sred[0] + sred[1] + sred[2] + sred[3]) *
                       (1.0f / ((float)B_N * (float)C_N)));
}

// ---------------------------------------------------------------------------
extern "C" void kernel_launch(void* const* d_in, const int* in_sizes, int n_in,
                              void* d_out, int out_size, void* d_ws, size_t ws_size,
                              hipStream_t stream) {
  const float* emb_i = (const float*)d_in[0];
  const float* emb_j = (const float*)d_in[1];
  const int* labels = (const int*)d_in[2];
  float* out = (float*)d_out;

  char* ws = (char*)d_ws;
  float* rn = (float*)ws;                                            // 32 KB
  unsigned short* proto = (unsigned short*)(ws + (size_t)32768);     // 2 MB
  float* p2 = (float*)(ws + (size_t)32768 + 2097152);                // 4 KB

  prep_kernel<<<dim3(C_N), 256, 0, stream>>>(emb_i, emb_j, labels, rn,
                                             proto, p2, out);
  gemm_loss_kernel<<<dim3(B_N / BM, C_N / BN), 256, 0, stream>>>(emb_j, proto,
                                                                 rn, p2, labels, out);
}